// Round 1
// baseline (2449.646 us; speedup 1.0000x reference)
//
#include <hip/hip_runtime.h>
#include <hip/hip_bf16.h>
#include <math.h>

#define BB 8
#define NN 1000
#define EE 16000
#define ETOT 17000   // E + N self loops
#define TPRED 12
#define FEAT 13
#define INDIM 14
#define HEADS 8
#define HG 256
#define C1 2048      // HEADS*HG
#define GO 13
#define HID 64

__device__ __forceinline__ float lrelu(float v){ return v > 0.f ? v : 0.2f*v; }

// ---------------- setup kernels (once per launch) ----------------

__global__ void k_init(const float* pm25, float* hn, float* xn, int* count){
    int i = blockIdx.x*blockDim.x + threadIdx.x;
    if (i < BB*NN*HID) hn[i] = 0.f;
    if (i < BB*NN){
        int b = i/NN, n = i%NN;
        xn[i] = pm25[(b*8 + 7)*NN + n];   // pm25_hist[b, -1, n, 0]
    }
    if (i < NN) count[i] = 0;
}

// Wsrc[k][h] = sum_d W1[k, h*256+d] * a_src[h,d]   (and Wdst)
__global__ void k_att1pre(const float* W1, const float* asrc, const float* adst,
                          float* Wsrc, float* Wdst){
    int k = blockIdx.x >> 3, h = blockIdx.x & 7;
    int tid = threadIdx.x;                 // 256 threads = 256 dims
    float wv = W1[k*C1 + h*HG + tid];
    float ps = wv * asrc[h*HG + tid];
    float pd = wv * adst[h*HG + tid];
    #pragma unroll
    for (int m=1;m<64;m<<=1){ ps += __shfl_xor(ps,m); pd += __shfl_xor(pd,m); }
    __shared__ float rs[4], rd[4];
    int w = tid>>6;
    if ((tid&63)==0){ rs[w]=ps; rd[w]=pd; }
    __syncthreads();
    if (tid==0){
        Wsrc[k*8+h] = rs[0]+rs[1]+rs[2]+rs[3];
        Wdst[k*8+h] = rd[0]+rd[1]+rd[2]+rd[3];
    }
}

// w2s[r] = sum_c W2[r,c]*a2src[c]  (and w2d)
__global__ void k_att2pre(const float* W2, const float* a2s, const float* a2d,
                          float* w2s, float* w2d){
    int r = blockIdx.x*blockDim.x + threadIdx.x;
    if (r < C1){
        float ss=0.f, dd=0.f;
        #pragma unroll
        for (int c=0;c<GO;c++){ float w=W2[r*GO+c]; ss+=w*a2s[c]; dd+=w*a2d[c]; }
        w2s[r]=ss; w2d[r]=dd;
    }
}

__global__ void k_count(const int* ei, int* count){
    int e = blockIdx.x*blockDim.x + threadIdx.x;
    if (e < ETOT){
        int dst = (e<EE) ? ei[EE+e] : (e-EE);
        atomicAdd(&count[dst], 1);
    }
}

__global__ void k_scan(const int* count, int* offs, int* cursor){
    __shared__ int s[1024];
    int tid = threadIdx.x;
    int myc = (tid<NN) ? count[tid] : 0;
    s[tid] = myc;
    __syncthreads();
    for (int d=1; d<1024; d<<=1){
        int v = (tid>=d) ? s[tid-d] : 0;
        __syncthreads();
        s[tid] += v;
        __syncthreads();
    }
    if (tid<NN){
        int off = s[tid] - myc;   // exclusive
        offs[tid] = off; cursor[tid] = off;
    }
    if (tid==NN-1) offs[NN] = s[tid];
}

__global__ void k_fill(const int* ei, int* cursor, int* csr_src){
    int e = blockIdx.x*blockDim.x + threadIdx.x;
    if (e < ETOT){
        int src = (e<EE) ? ei[e]    : (e-EE);
        int dst = (e<EE) ? ei[EE+e] : (e-EE);
        int pos = atomicAdd(&cursor[dst], 1);
        csr_src[pos] = src;
    }
}

// ---------------- per-step kernels ----------------

// h = x @ W1 (x = [xn, feat_t], 14 wide); also s_src = x@Wsrc, s_dst = x@Wdst
__global__ __launch_bounds__(256) void k_gat1mm(int t, const float* feat, const float* xn,
        const float* W1, const float* Wsrc, const float* Wdst,
        float* xh, float* ssrc, float* sdst){
    int tid = threadIdx.x;
    int b = blockIdx.x / 100;
    int tile = blockIdx.x % 100;
    float wreg[INDIM][8];
    #pragma unroll
    for (int k=0;k<INDIM;k++)
        #pragma unroll
        for (int j=0;j<8;j++)
            wreg[k][j] = W1[k*C1 + j*HG + tid];
    __shared__ float xs[INDIM];
    for (int ni=0; ni<10; ni++){
        int n = tile*10 + ni;
        __syncthreads();
        if (tid < INDIM){
            xs[tid] = (tid==0) ? xn[b*NN+n]
                    : feat[((size_t)(b*20 + 8 + t)*NN + n)*FEAT + (tid-1)];
        }
        __syncthreads();
        float acc[8];
        #pragma unroll
        for (int j=0;j<8;j++) acc[j]=0.f;
        #pragma unroll
        for (int k=0;k<INDIM;k++){
            float xv = xs[k];
            #pragma unroll
            for (int j=0;j<8;j++) acc[j] += xv * wreg[k][j];
        }
        size_t base = (size_t)(b*NN+n)*C1;
        #pragma unroll
        for (int j=0;j<8;j++) xh[base + j*HG + tid] = acc[j];
        if (tid < 2*HEADS){
            int h = tid & 7;
            const float* Wa = (tid<8) ? Wsrc : Wdst;
            float s = 0.f;
            #pragma unroll
            for (int k=0;k<INDIM;k++) s += xs[k]*Wa[k*8+h];
            if (tid<8) ssrc[(b*NN+n)*8+h] = s; else sdst[(b*NN+n)*8+h] = s;
        }
    }
}

// per-dst softmax over incoming edges (8 heads) + weighted aggregation + bias + elu
__global__ __launch_bounds__(256) void k_gat1agg(
        const float* xh, const float* ssrc, const float* sdst,
        const int* offs, const int* csr_src, const float* bias1,
        float* h1){
    int tid = threadIdx.x;
    int blk = blockIdx.x;
    int b = blk / NN, dstn = blk % NN;
    int base = offs[dstn], deg = offs[dstn+1]-base;
    __shared__ float sdl[8], mh[8], dh[8], red[4][8];
    __shared__ float alph[32][8];
    __shared__ int srcs[32];
    if (tid<8) sdl[tid] = sdst[(b*NN+dstn)*8+tid];
    __syncthreads();
    int head = tid & 7, slot = tid >> 3;
    int w = tid >> 6;
    // pass 1: max per head
    float mloc = -1e30f;
    for (int i=slot; i<deg; i+=32){
        int s = csr_src[base+i];
        mloc = fmaxf(mloc, lrelu(ssrc[(b*NN+s)*8+head] + sdl[head]));
    }
    mloc = fmaxf(mloc, __shfl_xor(mloc,8));
    mloc = fmaxf(mloc, __shfl_xor(mloc,16));
    mloc = fmaxf(mloc, __shfl_xor(mloc,32));
    if ((tid&63)<8) red[w][head] = mloc;
    __syncthreads();
    if (tid<8) mh[tid] = fmaxf(fmaxf(red[0][tid],red[1][tid]), fmaxf(red[2][tid],red[3][tid]));
    __syncthreads();
    // pass 2: denom per head
    float dloc = 0.f;
    for (int i=slot; i<deg; i+=32){
        int s = csr_src[base+i];
        dloc += __expf(lrelu(ssrc[(b*NN+s)*8+head] + sdl[head]) - mh[head]);
    }
    dloc += __shfl_xor(dloc,8); dloc += __shfl_xor(dloc,16); dloc += __shfl_xor(dloc,32);
    __syncthreads();
    if ((tid&63)<8) red[w][head] = dloc;
    __syncthreads();
    if (tid<8) dh[tid] = red[0][tid]+red[1][tid]+red[2][tid]+red[3][tid];
    __syncthreads();
    // pass 3: aggregate
    float acc[8];
    #pragma unroll
    for (int j=0;j<8;j++) acc[j]=0.f;
    for (int c0=0; c0<deg; c0+=32){
        int cn = min(32, deg-c0);
        if (tid < cn) srcs[tid] = csr_src[base+c0+tid];
        __syncthreads();
        if (slot < cn){
            int s = srcs[slot];
            float v = lrelu(ssrc[(b*NN+s)*8+head] + sdl[head]);
            alph[slot][head] = __expf(v - mh[head]) / dh[head];
        }
        __syncthreads();
        for (int i=0;i<cn;i++){
            int s = srcs[i];
            size_t hb = (size_t)(b*NN+s)*C1;
            #pragma unroll
            for (int j=0;j<8;j++) acc[j] += alph[i][j] * xh[hb + j*HG + tid];
        }
        __syncthreads();
    }
    size_t ob = (size_t)(b*NN+dstn)*C1;
    #pragma unroll
    for (int j=0;j<8;j++){
        float v = acc[j] + bias1[j*HG+tid];
        v = v > 0.f ? v : expm1f(v);
        h1[ob + j*HG + tid] = v;
    }
}

// h2 = h1 @ W2 (2048->13) plus folded attention cols 13,14
__global__ __launch_bounds__(256) void k_gat2mm(const float* h1, const float* W2,
        const float* w2s, const float* w2d,
        float* h2, float* s2src, float* s2dst){
    int tid = threadIdx.x;
    float wreg[8][15];
    #pragma unroll
    for (int k=0;k<8;k++){
        int r = k*HG + tid;
        #pragma unroll
        for (int c=0;c<GO;c++) wreg[k][c] = W2[r*GO+c];
        wreg[k][13] = w2s[r];
        wreg[k][14] = w2d[r];
    }
    __shared__ float red[15][HG];
    for (int i=0;i<16;i++){
        int bn = blockIdx.x*16 + i;
        size_t hb = (size_t)bn*C1;
        float hv[8];
        #pragma unroll
        for (int k=0;k<8;k++) hv[k] = h1[hb + k*HG + tid];
        float acc[15];
        #pragma unroll
        for (int c=0;c<15;c++) acc[c]=0.f;
        #pragma unroll
        for (int k=0;k<8;k++)
            #pragma unroll
            for (int c=0;c<15;c++) acc[c] += hv[k]*wreg[k][c];
        #pragma unroll
        for (int c=0;c<15;c++) red[c][tid] = acc[c];
        __syncthreads();
        int w = tid>>6, lane = tid&63;
        #pragma unroll
        for (int q=0;q<4;q++){
            int c = w + 4*q;
            if (c < 15){
                float v = red[c][lane] + red[c][lane+64] + red[c][lane+128] + red[c][lane+192];
                #pragma unroll
                for (int m=1;m<64;m<<=1) v += __shfl_xor(v,m);
                if (lane==0){
                    if (c<GO)        h2[bn*GO+c] = v;
                    else if (c==13)  s2src[bn]   = v;
                    else             s2dst[bn]   = v;
                }
            }
        }
        __syncthreads();
    }
}

// per-dst 1-head softmax + aggregation of h2 -> g (+bias2)
__global__ __launch_bounds__(64) void k_gat2agg(const float* h2, const float* s2src,
        const float* s2dst, const int* offs, const int* csr_src,
        const float* bias2, float* g){
    int lane = threadIdx.x;
    int blk = blockIdx.x;                    // bn
    int b = blk / NN, n = blk % NN;
    int base = offs[n], deg = offs[n+1]-base;
    float sdd = s2dst[blk];
    float mloc = -1e30f;
    for (int i=lane;i<deg;i+=64){
        int s = csr_src[base+i];
        mloc = fmaxf(mloc, lrelu(s2src[b*NN+s] + sdd));
    }
    #pragma unroll
    for (int m=1;m<64;m<<=1) mloc = fmaxf(mloc, __shfl_xor(mloc,m));
    float dloc = 0.f;
    for (int i=lane;i<deg;i+=64){
        int s = csr_src[base+i];
        dloc += __expf(lrelu(s2src[b*NN+s] + sdd) - mloc);
    }
    #pragma unroll
    for (int m=1;m<64;m<<=1) dloc += __shfl_xor(dloc,m);
    float gacc = 0.f;
    for (int i=0;i<deg;i++){
        int s = csr_src[base+i];
        float alpha = __expf(lrelu(s2src[b*NN+s] + sdd) - mloc) / dloc;
        if (lane < GO) gacc += alpha * h2[(b*NN+s)*GO + lane];
    }
    if (lane < GO) g[blk*GO + lane] = gacc + bias2[lane];
}

// GRU step + fc_out; writes hn, xn, and d_out[b, t, n]
__global__ __launch_bounds__(256) void k_gru(int t, const float* feat, const float* gbuf,
        const float* Wih, const float* Whh, const float* bih, const float* bhh,
        const float* fcw, const float* fcb,
        float* hn, float* xn, float* out){
    __shared__ float sWih[192*27];
    __shared__ float sWhh[192*65];     // row stride 65: bank-conflict-free
    __shared__ float sb[449];          // bih[192], bhh[192], fcw[64], fcb
    __shared__ float gxs[4][28];
    __shared__ float hs[4][64];
    int tid = threadIdx.x;
    for (int i=tid;i<192*27;i+=256) sWih[i] = Wih[i];
    for (int i=tid;i<192*64;i+=256) sWhh[(i>>6)*65 + (i&63)] = Whh[i];
    for (int i=tid;i<192;i+=256){ sb[i] = bih[i]; sb[192+i] = bhh[i]; }
    if (tid<64) sb[384+tid] = fcw[tid];
    if (tid==0) sb[448] = fcb[0];
    __syncthreads();
    int w = tid>>6, lane = tid&63;
    for (int i=0;i<4;i++){
        int bn = blockIdx.x*16 + i*4 + w;
        int b = bn/NN, n = bn%NN;
        if (lane < GO)       gxs[w][lane] = gbuf[bn*GO+lane];
        else if (lane == GO) gxs[w][GO]   = xn[bn];
        else if (lane < 27)  gxs[w][lane] = feat[((size_t)(b*20 + 8 + t)*NN + n)*FEAT + (lane-14)];
        hs[w][lane] = hn[bn*HID + lane];
        __syncthreads();
        float ir = sb[lane], iz = sb[64+lane], inn = sb[128+lane];
        #pragma unroll
        for (int c=0;c<27;c++){
            float xv = gxs[w][c];
            ir  += sWih[lane*27        + c]*xv;
            iz  += sWih[(64+lane)*27   + c]*xv;
            inn += sWih[(128+lane)*27  + c]*xv;
        }
        float hr = sb[192+lane], hz = sb[256+lane], hnv = sb[320+lane];
        #pragma unroll
        for (int j=0;j<64;j++){
            float hv = hs[w][j];
            hr  += sWhh[lane*65        + j]*hv;
            hz  += sWhh[(64+lane)*65   + j]*hv;
            hnv += sWhh[(128+lane)*65  + j]*hv;
        }
        float r  = 1.f/(1.f+__expf(-(ir+hr)));
        float z  = 1.f/(1.f+__expf(-(iz+hz)));
        float nv = tanhf(inn + r*hnv);
        float hold = hs[w][lane];
        float hnew = (1.f - z)*nv + z*hold;
        hn[bn*HID+lane] = hnew;
        float xv = hnew * sb[384+lane];
        #pragma unroll
        for (int m=1;m<64;m<<=1) xv += __shfl_xor(xv,m);
        if (lane==0){
            float res = xv + sb[448];
            xn[bn] = res;
            out[(b*TPRED + t)*NN + n] = res;
        }
        __syncthreads();
    }
}

// ---------------- host ----------------

extern "C" void kernel_launch(void* const* d_in, const int* in_sizes, int n_in,
                              void* d_out, int out_size, void* d_ws, size_t ws_size,
                              hipStream_t stream){
    const float* pm25 = (const float*)d_in[0];
    const float* feat = (const float*)d_in[1];
    const int*   ei   = (const int*)  d_in[2];
    const float* W1   = (const float*)d_in[3];
    const float* a1s  = (const float*)d_in[4];
    const float* a1d  = (const float*)d_in[5];
    const float* b1   = (const float*)d_in[6];
    const float* W2   = (const float*)d_in[7];
    const float* a2s  = (const float*)d_in[8];
    const float* a2d  = (const float*)d_in[9];
    const float* b2   = (const float*)d_in[10];
    const float* Wih  = (const float*)d_in[11];
    const float* Whh  = (const float*)d_in[12];
    const float* bih  = (const float*)d_in[13];
    const float* bhh  = (const float*)d_in[14];
    const float* fcw  = (const float*)d_in[15];
    const float* fcb  = (const float*)d_in[16];
    float* out = (float*)d_out;

    float* f = (float*)d_ws;
    size_t o = 0;
    float* xh    = f+o; o += (size_t)BB*NN*C1;
    float* h1    = f+o; o += (size_t)BB*NN*C1;
    float* ssrc1 = f+o; o += (size_t)BB*NN*8;
    float* sdst1 = f+o; o += (size_t)BB*NN*8;
    float* h2    = f+o; o += (size_t)BB*NN*GO;
    float* s2s   = f+o; o += (size_t)BB*NN;
    float* s2d   = f+o; o += (size_t)BB*NN;
    float* gb    = f+o; o += (size_t)BB*NN*GO;
    float* hn    = f+o; o += (size_t)BB*NN*HID;
    float* xn    = f+o; o += (size_t)BB*NN;
    float* Wsrc  = f+o; o += INDIM*8;
    float* Wdst  = f+o; o += INDIM*8;
    float* w2s   = f+o; o += C1;
    float* w2d   = f+o; o += C1;
    int* ibase  = (int*)(f+o);
    int* count  = ibase;
    int* cursor = ibase + NN;
    int* offs   = ibase + 2*NN;
    int* csr    = ibase + 2*NN + NN + 1;

    k_init   <<<2000,256,0,stream>>>(pm25, hn, xn, count);
    k_att1pre<<<112, 256,0,stream>>>(W1, a1s, a1d, Wsrc, Wdst);
    k_att2pre<<<8,   256,0,stream>>>(W2, a2s, a2d, w2s, w2d);
    k_count  <<<67,  256,0,stream>>>(ei, count);
    k_scan   <<<1,  1024,0,stream>>>(count, offs, cursor);
    k_fill   <<<67,  256,0,stream>>>(ei, cursor, csr);

    for (int t=0; t<TPRED; t++){
        k_gat1mm <<<800, 256,0,stream>>>(t, feat, xn, W1, Wsrc, Wdst, xh, ssrc1, sdst1);
        k_gat1agg<<<8000,256,0,stream>>>(xh, ssrc1, sdst1, offs, csr, b1, h1);
        k_gat2mm <<<500, 256,0,stream>>>(h1, W2, w2s, w2d, h2, s2s, s2d);
        k_gat2agg<<<8000, 64,0,stream>>>(h2, s2s, s2d, offs, csr, b2, gb);
        k_gru    <<<500, 256,0,stream>>>(t, feat, gb, Wih, Whh, bih, bhh, fcw, fcb, hn, xn, out);
    }
}

// Round 3
// 1863.752 us; speedup vs baseline: 1.3144x; 1.3144x over previous
//
#include <hip/hip_runtime.h>
#include <hip/hip_bf16.h>
#include <math.h>

#define BB 8
#define NN 1000
#define EE 16000
#define ETOT 17000   // E + N self loops
#define TPRED 12
#define FEAT 13
#define INDIM 14
#define HEADS 8
#define HG 256
#define C1 2048      // HEADS*HG
#define GO 13
#define HID 64

typedef unsigned int  uint32;
typedef unsigned short ushort16;
typedef uint32 uvec4 __attribute__((ext_vector_type(4)));

__device__ __forceinline__ float lrelu(float v){ return v > 0.f ? v : 0.2f*v; }

__device__ __forceinline__ ushort16 f2bf(float f){
    union { float f; uint32 u; } v; v.f = f;
    uint32 r = v.u + 0x7FFFu + ((v.u >> 16) & 1u);   // RNE
    return (ushort16)(r >> 16);
}
__device__ __forceinline__ uint32 pack2(float lo, float hi){
    return (uint32)f2bf(lo) | ((uint32)f2bf(hi) << 16);
}
__device__ __forceinline__ void cvt2(uint32 u, float& lo, float& hi){
    union { uint32 u; float f; } a, b;
    a.u = u << 16; b.u = u & 0xFFFF0000u;
    lo = a.f; hi = b.f;
}

// ---------------- setup kernels (once per launch) ----------------

__global__ void k_init(const float* pm25, float* hn, float* xn, int* count){
    int i = blockIdx.x*blockDim.x + threadIdx.x;
    if (i < BB*NN*HID) hn[i] = 0.f;
    if (i < BB*NN){
        int b = i/NN, n = i%NN;
        xn[i] = pm25[(b*8 + 7)*NN + n];   // pm25_hist[b, -1, n, 0]
    }
    if (i < NN) count[i] = 0;
}

// Wsrc[k][h] = sum_d W1[k, h*256+d] * a_src[h,d]   (and Wdst)
__global__ void k_att1pre(const float* W1, const float* asrc, const float* adst,
                          float* Wsrc, float* Wdst){
    int k = blockIdx.x >> 3, h = blockIdx.x & 7;
    int tid = threadIdx.x;                 // 256 threads = 256 dims
    float wv = W1[k*C1 + h*HG + tid];
    float ps = wv * asrc[h*HG + tid];
    float pd = wv * adst[h*HG + tid];
    #pragma unroll
    for (int m=1;m<64;m<<=1){ ps += __shfl_xor(ps,m); pd += __shfl_xor(pd,m); }
    __shared__ float rs[4], rd[4];
    int w = tid>>6;
    if ((tid&63)==0){ rs[w]=ps; rd[w]=pd; }
    __syncthreads();
    if (tid==0){
        Wsrc[k*8+h] = rs[0]+rs[1]+rs[2]+rs[3];
        Wdst[k*8+h] = rd[0]+rd[1]+rd[2]+rd[3];
    }
}

// w2s[r] = sum_c W2[r,c]*a2src[c]  (and w2d)
__global__ void k_att2pre(const float* W2, const float* a2s, const float* a2d,
                          float* w2s, float* w2d){
    int r = blockIdx.x*blockDim.x + threadIdx.x;
    if (r < C1){
        float ss=0.f, dd=0.f;
        #pragma unroll
        for (int c=0;c<GO;c++){ float w=W2[r*GO+c]; ss+=w*a2s[c]; dd+=w*a2d[c]; }
        w2s[r]=ss; w2d[r]=dd;
    }
}

__global__ void k_count(const int* ei, int* count){
    int e = blockIdx.x*blockDim.x + threadIdx.x;
    if (e < ETOT){
        int dst = (e<EE) ? ei[EE+e] : (e-EE);
        atomicAdd(&count[dst], 1);
    }
}

__global__ void k_scan(const int* count, int* offs, int* cursor){
    __shared__ int s[1024];
    int tid = threadIdx.x;
    int myc = (tid<NN) ? count[tid] : 0;
    s[tid] = myc;
    __syncthreads();
    for (int d=1; d<1024; d<<=1){
        int v = (tid>=d) ? s[tid-d] : 0;
        __syncthreads();
        s[tid] += v;
        __syncthreads();
    }
    if (tid<NN){
        int off = s[tid] - myc;   // exclusive
        offs[tid] = off; cursor[tid] = off;
    }
    if (tid==NN-1) offs[NN] = s[tid];
}

__global__ void k_fill(const int* ei, int* cursor, int* csr_src){
    int e = blockIdx.x*blockDim.x + threadIdx.x;
    if (e < ETOT){
        int src = (e<EE) ? ei[e]    : (e-EE);
        int dst = (e<EE) ? ei[EE+e] : (e-EE);
        int pos = atomicAdd(&cursor[dst], 1);
        csr_src[pos] = src;
    }
}

// ---------------- per-step kernels ----------------

// xh[bn, c] (bf16) = ([xn, feat_t] @ W1)[c], thread t owns channels 8t..8t+7
// also s_src = x@Wsrc, s_dst = x@Wdst (folded attention, f32)
__global__ __launch_bounds__(256) void k_gat1mm(int t, const float* feat, const float* xn,
        const float* W1, const float* Wsrc, const float* Wdst,
        ushort16* xh, float* ssrc, float* sdst){
    int tid = threadIdx.x;
    int b = blockIdx.x / 100;
    int tile = blockIdx.x % 100;
    float wreg[INDIM][8];
    #pragma unroll
    for (int k=0;k<INDIM;k++)
        #pragma unroll
        for (int j=0;j<8;j++)
            wreg[k][j] = W1[k*C1 + 8*tid + j];
    __shared__ float xs[INDIM];
    for (int ni=0; ni<10; ni++){
        int n = tile*10 + ni;
        __syncthreads();
        if (tid < INDIM){
            xs[tid] = (tid==0) ? xn[b*NN+n]
                    : feat[((size_t)(b*20 + 8 + t)*NN + n)*FEAT + (tid-1)];
        }
        __syncthreads();
        float acc[8];
        #pragma unroll
        for (int j=0;j<8;j++) acc[j]=0.f;
        #pragma unroll
        for (int k=0;k<INDIM;k++){
            float xv = xs[k];
            #pragma unroll
            for (int j=0;j<8;j++) acc[j] += xv * wreg[k][j];
        }
        size_t base = (size_t)(b*NN+n)*C1;
        uvec4 st;
        st.x = pack2(acc[0],acc[1]); st.y = pack2(acc[2],acc[3]);
        st.z = pack2(acc[4],acc[5]); st.w = pack2(acc[6],acc[7]);
        __builtin_nontemporal_store(st, (uvec4*)(xh + base + 8*tid));
        if (tid < 2*HEADS){
            int h = tid & 7;
            const float* Wa = (tid<8) ? Wsrc : Wdst;
            float s = 0.f;
            #pragma unroll
            for (int k=0;k<INDIM;k++) s += xs[k]*Wa[k*8+h];
            if (tid<8) ssrc[(b*NN+n)*8+h] = s; else sdst[(b*NN+n)*8+h] = s;
        }
    }
}

// per-dst softmax over incoming edges (8 heads) + weighted aggregation + bias + elu
// XCD affinity: b = blk&7 so each XCD's L2 holds one batch's xh slice (4MB bf16)
__global__ __launch_bounds__(256) void k_gat1agg(
        const ushort16* xh, const float* ssrc, const float* sdst,
        const int* offs, const int* csr_src, const float* bias1,
        ushort16* h1){
    int tid = threadIdx.x;
    int blk = blockIdx.x;
    int b = blk & 7, dstn = blk >> 3;
    int base = offs[dstn], deg = offs[dstn+1]-base;
    __shared__ float sdl[8], mh[8], dh[8], red[4][8];
    __shared__ float alph[32][8];
    __shared__ int srcs[32];
    if (tid<8) sdl[tid] = sdst[(b*NN+dstn)*8+tid];
    __syncthreads();
    int head = tid & 7, slot = tid >> 3;
    int w = tid >> 6;
    // pass 1: max per head
    float mloc = -1e30f;
    for (int i=slot; i<deg; i+=32){
        int s = csr_src[base+i];
        mloc = fmaxf(mloc, lrelu(ssrc[(b*NN+s)*8+head] + sdl[head]));
    }
    mloc = fmaxf(mloc, __shfl_xor(mloc,8));
    mloc = fmaxf(mloc, __shfl_xor(mloc,16));
    mloc = fmaxf(mloc, __shfl_xor(mloc,32));
    if ((tid&63)<8) red[w][head] = mloc;
    __syncthreads();
    if (tid<8) mh[tid] = fmaxf(fmaxf(red[0][tid],red[1][tid]), fmaxf(red[2][tid],red[3][tid]));
    __syncthreads();
    // pass 2: denom per head
    float dloc = 0.f;
    for (int i=slot; i<deg; i+=32){
        int s = csr_src[base+i];
        dloc += __expf(lrelu(ssrc[(b*NN+s)*8+head] + sdl[head]) - mh[head]);
    }
    dloc += __shfl_xor(dloc,8); dloc += __shfl_xor(dloc,16); dloc += __shfl_xor(dloc,32);
    __syncthreads();
    if ((tid&63)<8) red[w][head] = dloc;
    __syncthreads();
    if (tid<8) dh[tid] = red[0][tid]+red[1][tid]+red[2][tid]+red[3][tid];
    __syncthreads();
    // pass 3: aggregate. thread t owns channels 8t..8t+7 (head = t>>5)
    float acc[8];
    #pragma unroll
    for (int j=0;j<8;j++) acc[j]=0.f;
    int hh = tid >> 5;
    for (int c0=0; c0<deg; c0+=32){
        int cn = min(32, deg-c0);
        if (tid < cn) srcs[tid] = csr_src[base+c0+tid];
        __syncthreads();
        if (slot < cn){
            int s = srcs[slot];
            float v = lrelu(ssrc[(b*NN+s)*8+head] + sdl[head]);
            alph[slot][head] = __expf(v - mh[head]) / dh[head];
        }
        __syncthreads();
        for (int i=0;i<cn;i++){
            int s = srcs[i];
            float a = alph[i][hh];
            const uvec4* xr = (const uvec4*)(xh + (size_t)(b*NN+s)*C1 + 8*tid);
            uvec4 u = *xr;
            float f0,f1,f2,f3,f4,f5,f6,f7;
            cvt2(u.x,f0,f1); cvt2(u.y,f2,f3); cvt2(u.z,f4,f5); cvt2(u.w,f6,f7);
            acc[0] += a*f0; acc[1] += a*f1; acc[2] += a*f2; acc[3] += a*f3;
            acc[4] += a*f4; acc[5] += a*f5; acc[6] += a*f6; acc[7] += a*f7;
        }
        __syncthreads();
    }
    size_t ob = (size_t)(b*NN+dstn)*C1;
    float r[8];
    #pragma unroll
    for (int j=0;j<8;j++){
        float v = acc[j] + bias1[8*tid+j];
        r[j] = v > 0.f ? v : expm1f(v);
    }
    uvec4 st;
    st.x = pack2(r[0],r[1]); st.y = pack2(r[2],r[3]);
    st.z = pack2(r[4],r[5]); st.w = pack2(r[6],r[7]);
    __builtin_nontemporal_store(st, (uvec4*)(h1 + ob + 8*tid));
}

// h2 = h1 @ W2 (2048->13) plus folded attention cols 13,14. h1 bf16.
__global__ __launch_bounds__(256) void k_gat2mm(const ushort16* h1, const float* W2,
        const float* w2s, const float* w2d,
        float* h2, float* s2src, float* s2dst){
    int tid = threadIdx.x;
    float wreg[8][15];
    #pragma unroll
    for (int j=0;j<8;j++){
        int r = 8*tid + j;
        #pragma unroll
        for (int c=0;c<GO;c++) wreg[j][c] = W2[r*GO+c];
        wreg[j][13] = w2s[r];
        wreg[j][14] = w2d[r];
    }
    __shared__ float red[15][HG];
    for (int i=0;i<16;i++){
        int bn = blockIdx.x*16 + i;
        size_t hb = (size_t)bn*C1;
        uvec4 u = __builtin_nontemporal_load((const uvec4*)(h1 + hb + 8*tid));
        float hv[8];
        cvt2(u.x,hv[0],hv[1]); cvt2(u.y,hv[2],hv[3]);
        cvt2(u.z,hv[4],hv[5]); cvt2(u.w,hv[6],hv[7]);
        float acc[15];
        #pragma unroll
        for (int c=0;c<15;c++) acc[c]=0.f;
        #pragma unroll
        for (int j=0;j<8;j++)
            #pragma unroll
            for (int c=0;c<15;c++) acc[c] += hv[j]*wreg[j][c];
        #pragma unroll
        for (int c=0;c<15;c++) red[c][tid] = acc[c];
        __syncthreads();
        int w = tid>>6, lane = tid&63;
        #pragma unroll
        for (int q=0;q<4;q++){
            int c = w + 4*q;
            if (c < 15){
                float v = red[c][lane] + red[c][lane+64] + red[c][lane+128] + red[c][lane+192];
                #pragma unroll
                for (int m=1;m<64;m<<=1) v += __shfl_xor(v,m);
                if (lane==0){
                    if (c<GO)        h2[bn*GO+c] = v;
                    else if (c==13)  s2src[bn]   = v;
                    else             s2dst[bn]   = v;
                }
            }
        }
        __syncthreads();
    }
}

// per-dst 1-head softmax + aggregation of h2 -> g (+bias2). Edge-parallel.
__global__ __launch_bounds__(64) void k_gat2agg(const float* h2, const float* s2src,
        const float* s2dst, const int* offs, const int* csr_src,
        const float* bias2, float* g){
    int lane = threadIdx.x;
    int blk = blockIdx.x;
    int b = blk & 7, n = blk >> 3;
    int bn = b*NN + n;
    int base = offs[n], deg = offs[n+1]-base;
    float sdd = s2dst[bn];
    float mloc = -1e30f;
    for (int i=lane;i<deg;i+=64){
        int s = csr_src[base+i];
        mloc = fmaxf(mloc, lrelu(s2src[b*NN+s] + sdd));
    }
    #pragma unroll
    for (int m=1;m<64;m<<=1) mloc = fmaxf(mloc, __shfl_xor(mloc,m));
    float dloc = 0.f;
    for (int i=lane;i<deg;i+=64){
        int s = csr_src[base+i];
        dloc += __expf(lrelu(s2src[b*NN+s] + sdd) - mloc);
    }
    #pragma unroll
    for (int m=1;m<64;m<<=1) dloc += __shfl_xor(dloc,m);
    float rd = 1.f / dloc;
    float acc[GO];
    #pragma unroll
    for (int c=0;c<GO;c++) acc[c]=0.f;
    for (int i=lane;i<deg;i+=64){
        int s = csr_src[base+i];
        float al = __expf(lrelu(s2src[b*NN+s] + sdd) - mloc) * rd;
        const float* hr = h2 + (size_t)(b*NN+s)*GO;
        #pragma unroll
        for (int c=0;c<GO;c++) acc[c] += al*hr[c];
    }
    #pragma unroll
    for (int c=0;c<GO;c++){
        #pragma unroll
        for (int m=1;m<64;m<<=1) acc[c] += __shfl_xor(acc[c],m);
    }
    if (lane==0){
        #pragma unroll
        for (int c=0;c<GO;c++) g[bn*GO+c] = acc[c] + bias2[c];
    }
}

// GRU step + fc_out; writes hn, xn, and d_out[b, t, n]
__global__ __launch_bounds__(256) void k_gru(int t, const float* feat, const float* gbuf,
        const float* Wih, const float* Whh, const float* bih, const float* bhh,
        const float* fcw, const float* fcb,
        float* hn, float* xn, float* out){
    __shared__ float sWih[192*27];
    __shared__ float sWhh[192*65];     // row stride 65: bank-conflict-free
    __shared__ float sb[449];          // bih[192], bhh[192], fcw[64], fcb
    __shared__ float gxs[4][28];
    __shared__ float hs[4][64];
    int tid = threadIdx.x;
    for (int i=tid;i<192*27;i+=256) sWih[i] = Wih[i];
    for (int i=tid;i<192*64;i+=256) sWhh[(i>>6)*65 + (i&63)] = Whh[i];
    for (int i=tid;i<192;i+=256){ sb[i] = bih[i]; sb[192+i] = bhh[i]; }
    if (tid<64) sb[384+tid] = fcw[tid];
    if (tid==0) sb[448] = fcb[0];
    __syncthreads();
    int w = tid>>6, lane = tid&63;
    for (int i=0;i<4;i++){
        int bn = blockIdx.x*16 + i*4 + w;
        int b = bn/NN, n = bn%NN;
        if (lane < GO)       gxs[w][lane] = gbuf[bn*GO+lane];
        else if (lane == GO) gxs[w][GO]   = xn[bn];
        else if (lane < 27)  gxs[w][lane] = feat[((size_t)(b*20 + 8 + t)*NN + n)*FEAT + (lane-14)];
        hs[w][lane] = hn[bn*HID + lane];
        __syncthreads();
        float ir = sb[lane], iz = sb[64+lane], inn = sb[128+lane];
        #pragma unroll
        for (int c=0;c<27;c++){
            float xv = gxs[w][c];
            ir  += sWih[lane*27        + c]*xv;
            iz  += sWih[(64+lane)*27   + c]*xv;
            inn += sWih[(128+lane)*27  + c]*xv;
        }
        float hr = sb[192+lane], hz = sb[256+lane], hnv = sb[320+lane];
        #pragma unroll
        for (int j=0;j<64;j++){
            float hv = hs[w][j];
            hr  += sWhh[lane*65        + j]*hv;
            hz  += sWhh[(64+lane)*65   + j]*hv;
            hnv += sWhh[(128+lane)*65  + j]*hv;
        }
        float r  = 1.f/(1.f+__expf(-(ir+hr)));
        float z  = 1.f/(1.f+__expf(-(iz+hz)));
        float nv = tanhf(inn + r*hnv);
        float hold = hs[w][lane];
        float hnew = (1.f - z)*nv + z*hold;
        hn[bn*HID+lane] = hnew;
        float xv = hnew * sb[384+lane];
        #pragma unroll
        for (int m=1;m<64;m<<=1) xv += __shfl_xor(xv,m);
        if (lane==0){
            float res = xv + sb[448];
            xn[bn] = res;
            out[(b*TPRED + t)*NN + n] = res;
        }
        __syncthreads();
    }
}

// ---------------- host ----------------

extern "C" void kernel_launch(void* const* d_in, const int* in_sizes, int n_in,
                              void* d_out, int out_size, void* d_ws, size_t ws_size,
                              hipStream_t stream){
    const float* pm25 = (const float*)d_in[0];
    const float* feat = (const float*)d_in[1];
    const int*   ei   = (const int*)  d_in[2];
    const float* W1   = (const float*)d_in[3];
    const float* a1s  = (const float*)d_in[4];
    const float* a1d  = (const float*)d_in[5];
    const float* b1   = (const float*)d_in[6];
    const float* W2   = (const float*)d_in[7];
    const float* a2s  = (const float*)d_in[8];
    const float* a2d  = (const float*)d_in[9];
    const float* b2   = (const float*)d_in[10];
    const float* Wih  = (const float*)d_in[11];
    const float* Whh  = (const float*)d_in[12];
    const float* bih  = (const float*)d_in[13];
    const float* bhh  = (const float*)d_in[14];
    const float* fcw  = (const float*)d_in[15];
    const float* fcb  = (const float*)d_in[16];
    float* out = (float*)d_out;

    float* f = (float*)d_ws;
    size_t o = 0;
    ushort16* xh = (ushort16*)(f+o); o += (size_t)BB*NN*C1/2;   // bf16
    ushort16* h1 = (ushort16*)(f+o); o += (size_t)BB*NN*C1/2;   // bf16
    float* ssrc1 = f+o; o += (size_t)BB*NN*8;
    float* sdst1 = f+o; o += (size_t)BB*NN*8;
    float* h2    = f+o; o += (size_t)BB*NN*GO;
    float* s2s   = f+o; o += (size_t)BB*NN;
    float* s2d   = f+o; o += (size_t)BB*NN;
    float* gb    = f+o; o += (size_t)BB*NN*GO;
    float* hn    = f+o; o += (size_t)BB*NN*HID;
    float* xn    = f+o; o += (size_t)BB*NN;
    float* Wsrc  = f+o; o += INDIM*8;
    float* Wdst  = f+o; o += INDIM*8;
    float* w2s   = f+o; o += C1;
    float* w2d   = f+o; o += C1;
    int* ibase  = (int*)(f+o);
    int* count  = ibase;
    int* cursor = ibase + NN;
    int* offs   = ibase + 2*NN;
    int* csr    = ibase + 2*NN + NN + 1;

    k_init   <<<2000,256,0,stream>>>(pm25, hn, xn, count);
    k_att1pre<<<112, 256,0,stream>>>(W1, a1s, a1d, Wsrc, Wdst);
    k_att2pre<<<8,   256,0,stream>>>(W2, a2s, a2d, w2s, w2d);
    k_count  <<<67,  256,0,stream>>>(ei, count);
    k_scan   <<<1,  1024,0,stream>>>(count, offs, cursor);
    k_fill   <<<67,  256,0,stream>>>(ei, cursor, csr);

    for (int t=0; t<TPRED; t++){
        k_gat1mm <<<800, 256,0,stream>>>(t, feat, xn, W1, Wsrc, Wdst, xh, ssrc1, sdst1);
        k_gat1agg<<<8000,256,0,stream>>>(xh, ssrc1, sdst1, offs, csr, b1, h1);
        k_gat2mm <<<500, 256,0,stream>>>(h1, W2, w2s, w2d, h2, s2s, s2d);
        k_gat2agg<<<8000, 64,0,stream>>>(h2, s2s, s2d, offs, csr, b2, gb);
        k_gru    <<<500, 256,0,stream>>>(t, feat, gb, Wih, Whh, bih, bhh, fcw, fcb, hn, xn, out);
    }
}